// Round 1
// baseline (1047.983 us; speedup 1.0000x reference)
//
#include <hip/hip_runtime.h>
#include <hip/hip_bf16.h>

// Problem dims
#define NB 128      // batch B
#define NA 512      // attention positions A (== K_out of attend)
#define NR 512      // R == IN
#define NOUT 10000

typedef __attribute__((ext_vector_type(8))) short bf16x8;
typedef __attribute__((ext_vector_type(4))) float f32x4;

__device__ inline short f2bf(float f) {
  __hip_bfloat16 h = __float2bfloat16(f);
  return *reinterpret_cast<const short*>(&h);
}

__device__ inline float fast_tanh(float x) {
  float e = __expf(2.0f * x);
  return 1.0f - 2.0f / (e + 1.0f);
}
__device__ inline float fast_sigmoid(float x) {
  return 1.0f / (1.0f + __expf(-x));
}

// load 8 consecutive fp32 (32B aligned) and convert to bf16x8
__device__ inline bf16x8 cvt8(const float* __restrict__ p) {
  f32x4 a = *(const f32x4*)p;
  f32x4 b = *(const f32x4*)(p + 4);
  bf16x8 r;
  r[0] = f2bf(a[0]); r[1] = f2bf(a[1]); r[2] = f2bf(a[2]); r[3] = f2bf(a[3]);
  r[4] = f2bf(b[0]); r[5] = f2bf(b[1]); r[6] = f2bf(b[2]); r[7] = f2bf(b[3]);
  return r;
}

// ---------------------------------------------------------------------------
// score_pass: for one attend weight-set, compute scores[b][a] for up to two
// h-variants, fusing the big GEMM v = att @ Wa^T with the tanh/Wd reduction.
// Transposed GEMM: M = k_out (512, split over 8 waves), N = att rows
// (64 per block), K = r (512). att tile staged fp32->bf16 in LDS.
// ---------------------------------------------------------------------------
__global__ __launch_bounds__(512) void score_pass(
    const float* __restrict__ att,   // [B*A][R] fp32
    const float* __restrict__ Wa,    // [A][R]   fp32 (a2a weights)
    const float* __restrict__ ba,    // [A]
    const float* __restrict__ Wd,    // [A]      (d2d_w row 0)
    const float* __restrict__ hh1,   // [B][A] == flat[b*512+a]
    const float* __restrict__ hh2,   // may be null
    float* __restrict__ sc1,         // [B*A]
    float* __restrict__ sc2)         // may be null
{
  __shared__ short Lb[64 * 40];            // 64 att-rows x 32 k, stride 40 (pad)
  __shared__ float sred[8][4][16][2];
  const int tid = threadIdx.x;
  const int wv = tid >> 6;
  const int lane = tid & 63;
  const int l15 = lane & 15, l4 = lane >> 4;
  const int row0 = blockIdx.x * 64;        // global att-row base
  const int mrow0 = wv * 64;               // k_out base for this wave
  const int scol = tid >> 3, skg = tid & 7;
  const bool has2 = (hh2 != nullptr);

  f32x4 acc[4][4] = {};

  for (int kk = 0; kk < 512; kk += 32) {
    __syncthreads();
    // stage att 64x32 fp32 -> bf16 LDS
    const float4 av = *(const float4*)(att + (size_t)(row0 + scol) * 512 + kk + skg * 4);
    short4 sv;
    sv.x = f2bf(av.x); sv.y = f2bf(av.y); sv.z = f2bf(av.z); sv.w = f2bf(av.w);
    *(short4*)(&Lb[scol * 40 + skg * 4]) = sv;
    __syncthreads();

    bf16x8 afr[4];
#pragma unroll
    for (int mf = 0; mf < 4; mf++)
      afr[mf] = cvt8(Wa + (size_t)(mrow0 + mf * 16 + l15) * 512 + kk + l4 * 8);
    bf16x8 bfr[4];
#pragma unroll
    for (int nf = 0; nf < 4; nf++)
      bfr[nf] = *(const bf16x8*)(&Lb[(nf * 16 + l15) * 40 + l4 * 8]);
#pragma unroll
    for (int mf = 0; mf < 4; mf++)
#pragma unroll
      for (int nf = 0; nf < 4; nf++)
        acc[mf][nf] = __builtin_amdgcn_mfma_f32_16x16x32_bf16(afr[mf], bfr[nf], acc[mf][nf], 0, 0, 0);
  }

  // epilogue: scores[col] = sum_k tanh(v + hh[col]) * Wd[k]
  float h1v[4], h2v[4];
#pragma unroll
  for (int nf = 0; nf < 4; nf++) {
    const int colg = row0 + nf * 16 + l15;   // == b*512 + a
    h1v[nf] = hh1[colg];
    h2v[nf] = has2 ? hh2[colg] : 0.f;
  }
  float p1[4] = {0, 0, 0, 0}, p2[4] = {0, 0, 0, 0};
#pragma unroll
  for (int mf = 0; mf < 4; mf++) {
#pragma unroll
    for (int r = 0; r < 4; r++) {
      const int krow = mrow0 + mf * 16 + l4 * 4 + r;
      const float bav = ba[krow];
      const float wdv = Wd[krow];
#pragma unroll
      for (int nf = 0; nf < 4; nf++) {
        const float v = acc[mf][nf][r] + bav;
        p1[nf] += fast_tanh(v + h1v[nf]) * wdv;
        if (has2) p2[nf] += fast_tanh(v + h2v[nf]) * wdv;
      }
    }
  }
#pragma unroll
  for (int nf = 0; nf < 4; nf++) {
    float x1 = p1[nf];
    x1 += __shfl_xor(x1, 16); x1 += __shfl_xor(x1, 32);
    float x2 = p2[nf];
    x2 += __shfl_xor(x2, 16); x2 += __shfl_xor(x2, 32);
    if (l4 == 0) { sred[wv][nf][l15][0] = x1; sred[wv][nf][l15][1] = x2; }
  }
  __syncthreads();
  if (tid < 128) {
    const int v2 = tid >> 6, nf = (tid >> 4) & 3, c = tid & 15;
    if (v2 == 0 || has2) {
      float s = 0.f;
#pragma unroll
      for (int w = 0; w < 8; w++) s += sred[w][nf][c][v2];
      float* dst = v2 ? sc2 : sc1;
      dst[row0 + nf * 16 + c] = s;
    }
  }
}

// ---------------------------------------------------------------------------
// Generic GEMM: out[n][m] = sum_k A[m][k]*B[n][k] + bias[m]
// A fp32 [M][512] (rows clamped to Mclamp for tail), B bf16 [N][512].
// Block: 256 thr (4 waves along M, wave tile 64x32). grid = (ceil(M/256), N/32)
// ---------------------------------------------------------------------------
__global__ __launch_bounds__(256) void gemm_tn512(
    const float* __restrict__ A, const short* __restrict__ Bb,
    const float* __restrict__ bias, float* __restrict__ out,
    const int M, const int Mclamp)
{
  const int tid = threadIdx.x;
  const int wv = tid >> 6, lane = tid & 63;
  const int l15 = lane & 15, l4 = lane >> 4;
  const int mrow0 = blockIdx.x * 256 + wv * 64;
  const int ncol0 = blockIdx.y * 32;
  f32x4 acc[4][2] = {};
  for (int kk = 0; kk < 512; kk += 32) {
    bf16x8 afr[4];
#pragma unroll
    for (int mf = 0; mf < 4; mf++) {
      int row = mrow0 + mf * 16 + l15;
      row = row > Mclamp ? Mclamp : row;
      afr[mf] = cvt8(A + (size_t)row * 512 + kk + l4 * 8);
    }
    bf16x8 bfr[2];
#pragma unroll
    for (int nf = 0; nf < 2; nf++)
      bfr[nf] = *(const bf16x8*)(Bb + (size_t)(ncol0 + nf * 16 + l15) * 512 + kk + l4 * 8);
#pragma unroll
    for (int mf = 0; mf < 4; mf++)
#pragma unroll
      for (int nf = 0; nf < 2; nf++)
        acc[mf][nf] = __builtin_amdgcn_mfma_f32_16x16x32_bf16(afr[mf], bfr[nf], acc[mf][nf], 0, 0, 0);
  }
#pragma unroll
  for (int mf = 0; mf < 4; mf++)
#pragma unroll
    for (int r = 0; r < 4; r++) {
      const int row = mrow0 + mf * 16 + l4 * 4 + r;
      if (row < M) {
        const float bv = bias ? bias[row] : 0.f;
#pragma unroll
        for (int nf = 0; nf < 2; nf++) {
          const int col = ncol0 + nf * 16 + l15;
          out[(size_t)col * M + row] = acc[mf][nf][r] + bv;
        }
      }
    }
}

// ---------------------------------------------------------------------------
// LSTM gates GEMM: sums[b][n] = xt@i2h[n] + prev_h@h2h[n] + ar@a2h[n] + biases
// M=4096, N=128, K=3*512 (three separate A/B sources).
// ---------------------------------------------------------------------------
__global__ __launch_bounds__(256) void gates_gemm(
    const float* __restrict__ A1, const float* __restrict__ A2, const float* __restrict__ A3,
    const short* __restrict__ B1, const short* __restrict__ B2, const short* __restrict__ B3,
    const float* __restrict__ b1, const float* __restrict__ b2, const float* __restrict__ b3,
    float* __restrict__ out)
{
  const int tid = threadIdx.x;
  const int wv = tid >> 6, lane = tid & 63;
  const int l15 = lane & 15, l4 = lane >> 4;
  const int mrow0 = blockIdx.x * 256 + wv * 64;
  const int ncol0 = blockIdx.y * 32;
  f32x4 acc[4][2] = {};
#pragma unroll 1
  for (int seg = 0; seg < 3; seg++) {
    const float* As = seg == 0 ? A1 : (seg == 1 ? A2 : A3);
    const short* Bs = seg == 0 ? B1 : (seg == 1 ? B2 : B3);
    for (int kk = 0; kk < 512; kk += 32) {
      bf16x8 afr[4];
#pragma unroll
      for (int mf = 0; mf < 4; mf++)
        afr[mf] = cvt8(As + (size_t)(mrow0 + mf * 16 + l15) * 512 + kk + l4 * 8);
      bf16x8 bfr[2];
#pragma unroll
      for (int nf = 0; nf < 2; nf++)
        bfr[nf] = *(const bf16x8*)(Bs + (size_t)(ncol0 + nf * 16 + l15) * 512 + kk + l4 * 8);
#pragma unroll
      for (int mf = 0; mf < 4; mf++)
#pragma unroll
        for (int nf = 0; nf < 2; nf++)
          acc[mf][nf] = __builtin_amdgcn_mfma_f32_16x16x32_bf16(afr[mf], bfr[nf], acc[mf][nf], 0, 0, 0);
    }
  }
#pragma unroll
  for (int mf = 0; mf < 4; mf++)
#pragma unroll
    for (int r = 0; r < 4; r++) {
      const int row = mrow0 + mf * 16 + l4 * 4 + r;
      const float bv = b1[row] + b2[row] + b3[row];
#pragma unroll
      for (int nf = 0; nf < 2; nf++) {
        const int col = ncol0 + nf * 16 + l15;
        out[(size_t)col * 4096 + row] = acc[mf][nf][r] + bv;
      }
    }
}

// softmax over rows of 512 (in place)
__global__ __launch_bounds__(512) void softmax512(float* __restrict__ d)
{
  const int row = blockIdx.x, t = threadIdx.x;
  const int lane = t & 63, wv = t >> 6;
  __shared__ float red[8];
  float x = d[(size_t)row * 512 + t];
  float m = x;
#pragma unroll
  for (int o = 32; o >= 1; o >>= 1) m = fmaxf(m, __shfl_xor(m, o));
  if (lane == 0) red[wv] = m;
  __syncthreads();
  float gm = red[0];
#pragma unroll
  for (int i = 1; i < 8; i++) gm = fmaxf(gm, red[i]);
  const float e = __expf(x - gm);
  float s = e;
#pragma unroll
  for (int o = 32; o >= 1; o >>= 1) s += __shfl_xor(s, o);
  __syncthreads();
  if (lane == 0) red[wv] = s;
  __syncthreads();
  float gs = 0.f;
#pragma unroll
  for (int i = 0; i < 8; i++) gs += red[i];
  d[(size_t)row * 512 + t] = e / gs;
}

// att_res[b][r] = sum_a att[b][a][r] * w[b][a]  (split over 4 a-chunks, atomic)
__global__ __launch_bounds__(512) void att_res_pass(
    const float* __restrict__ att,
    const float* __restrict__ w1, const float* __restrict__ w2,
    float* __restrict__ ar1, float* __restrict__ ar2)
{
  const int r = threadIdx.x;
  const int chunk = blockIdx.x;
  const int b = blockIdx.y;
  const bool has2 = (w2 != nullptr);
  float a1 = 0.f, a2 = 0.f;
  const int abase = chunk * 128;
  for (int a = 0; a < 128; a++) {
    const int ai = abase + a;
    const float x = att[((size_t)b * 512 + ai) * 512 + r];
    a1 += x * w1[b * 512 + ai];
    if (has2) a2 += x * w2[b * 512 + ai];
  }
  atomicAdd(&ar1[b * 512 + r], a1);
  if (has2) atomicAdd(&ar2[b * 512 + r], a2);
}

// gate nonlinearities + per-p LSTM cell + mean over P
__global__ __launch_bounds__(256) void lstm_combine(
    const float* __restrict__ sums, const float* __restrict__ prev_c,
    float* __restrict__ out_c, float* __restrict__ nh_f, short* __restrict__ nh_bf)
{
  const int idx = blockIdx.x * 256 + threadIdx.x;   // 65536
  const int b = idx >> 9, r = idx & 511;
  const float* sb = sums + (size_t)b * 4096;
  const float pc = prev_c[idx];
  float nc = 0.f, nh = 0.f;
#pragma unroll
  for (int p = 0; p < 2; p++) {
    const float si = sb[p * 2048 + r];
    const float sf = sb[p * 2048 + 512 + r];
    const float so = sb[p * 2048 + 1024 + r];
    const float st = sb[p * 2048 + 1536 + r];
    const float ig = fast_sigmoid(si), fg = fast_sigmoid(sf), og = fast_sigmoid(so);
    const float it = fast_tanh(st);
    const float c = fg * pc + ig * it;
    const float h = og * fast_tanh(c);
    nc += c; nh += h;
  }
  nc *= 0.5f; nh *= 0.5f;
  out_c[idx] = nc;
  nh_f[idx] = nh;
  nh_bf[idx] = f2bf(nh);
}

// out_f = a + b (fp32); optional bf16 copy
__global__ __launch_bounds__(256) void add_store(
    const float* __restrict__ a, const float* __restrict__ b,
    float* __restrict__ of, short* __restrict__ ob)
{
  const int idx = blockIdx.x * 256 + threadIdx.x;
  const float v = a[idx] + b[idx];
  of[idx] = v;
  if (ob) ob[idx] = f2bf(v);
}

// bf16 convert with optional add of second fp32 source (n = 65536 fixed grid)
__global__ __launch_bounds__(256) void cvt_bf(
    const float* __restrict__ src, const float* __restrict__ add,
    short* __restrict__ dst)
{
  const int idx = blockIdx.x * 256 + threadIdx.x;
  float v = src[idx];
  if (add) v += add[idx];
  dst[idx] = f2bf(v);
}

// log_softmax over rows of 10000
__global__ __launch_bounds__(256) void logsoftmax_k(
    const float* __restrict__ logits, float* __restrict__ out)
{
  const int b = blockIdx.x, t = threadIdx.x;
  const int lane = t & 63, wv = t >> 6;
  __shared__ float red[4];
  const float* p = logits + (size_t)b * NOUT;
  float m = -3.4e38f;
  for (int j = t; j < NOUT; j += 256) m = fmaxf(m, p[j]);
#pragma unroll
  for (int o = 32; o >= 1; o >>= 1) m = fmaxf(m, __shfl_xor(m, o));
  if (lane == 0) red[wv] = m;
  __syncthreads();
  m = fmaxf(fmaxf(red[0], red[1]), fmaxf(red[2], red[3]));
  float s = 0.f;
  for (int j = t; j < NOUT; j += 256) s += __expf(p[j] - m);
#pragma unroll
  for (int o = 32; o >= 1; o >>= 1) s += __shfl_xor(s, o);
  __syncthreads();
  if (lane == 0) red[wv] = s;
  __syncthreads();
  s = red[0] + red[1] + red[2] + red[3];
  const float lg = m + __logf(s);
  float* q = out + (size_t)b * NOUT;
  for (int j = t; j < NOUT; j += 256) q[j] = p[j] - lg;
}

extern "C" void kernel_launch(void* const* d_in, const int* in_sizes, int n_in,
                              void* d_out, int out_size, void* d_ws, size_t ws_size,
                              hipStream_t stream)
{
  const float* x      = (const float*)d_in[0];
  const float* att    = (const float*)d_in[1];
  const float* inp    = (const float*)d_in[2];
  const float* a2a_w  = (const float*)d_in[3];
  const float* a2a_b  = (const float*)d_in[4];
  const float* h2a_w  = (const float*)d_in[5];
  const float* h2a_b  = (const float*)d_in[6];
  const float* d2d_w  = (const float*)d_in[7];
  const float* a2a1_w = (const float*)d_in[9];
  const float* a2a1_b = (const float*)d_in[10];
  const float* h2a1_w = (const float*)d_in[11];
  const float* h2a1_b = (const float*)d_in[12];
  const float* d2d1_w = (const float*)d_in[13];
  const float* i2h_w  = (const float*)d_in[15];
  const float* i2h_b  = (const float*)d_in[16];
  const float* h2h_w  = (const float*)d_in[17];
  const float* h2h_b  = (const float*)d_in[18];
  const float* a2h_w  = (const float*)d_in[19];
  const float* a2h_b  = (const float*)d_in[20];
  const float* proj_w = (const float*)d_in[21];
  const float* proj_b = (const float*)d_in[22];
  float* out = (float*)d_out;

  const int S = NB * NA;     // 65536
  float* wsf = (float*)d_ws;
  float* hhA = wsf;                // [S] each
  float* hhB = hhA + S;
  float* hhC = hhB + S;
  float* hhD = hhC + S;
  float* scA = hhD + S;
  float* scB = scA + S;
  float* scC = scB + S;
  float* scD = scC + S;
  float* arA = scD + S;
  float* arB = arA + S;
  float* arC = arB + S;
  float* arD = arC + S;
  float* sums   = arD + S;               // 128*4096
  float* logits = sums + NB * 4096;      // 128*10000
  float* nh0f   = logits + (size_t)NB * NOUT;
  float* nh1f   = nh0f + S;
  short* bfb    = (short*)(nh1f + S);
  short* xt0b = bfb;
  short* xt1b = xt0b + S;
  short* ph0b = xt1b + S;
  short* ph1b = ph0b + S;
  short* arAb = ph1b + S;
  short* arBb = arAb + S;
  short* nh0b = arBb + S;
  short* nh1b = nh0b + S;
  short* th1b = nh1b + S;

  const float* prev_c0 = inp;
  const float* prev_h0 = inp + S;
  const float* prev_c1 = inp + 2 * S;
  const float* prev_h1 = inp + 3 * S;
  const size_t LSTRIDE_W = (size_t)2 * 2048 * 512;   // per-layer weight stride
  const size_t LSTRIDE_B = 4096;

  // zero the att_res accumulators (atomic targets)
  hipMemsetAsync(arA, 0, (size_t)4 * S * sizeof(float), stream);

  // bf16 activations known up-front
  cvt_bf<<<256, 256, 0, stream>>>(x, nullptr, xt0b);
  cvt_bf<<<256, 256, 0, stream>>>(prev_h0, nullptr, ph0b);
  cvt_bf<<<256, 256, 0, stream>>>(prev_h1, nullptr, ph1b);

  // hh for the two set-0 attends (both h's known)
  gemm_tn512<<<dim3(2, 4), 256, 0, stream>>>(h2a_w, ph0b, h2a_b, hhA, 512, 511);
  gemm_tn512<<<dim3(2, 4), 256, 0, stream>>>(h2a_w, ph1b, h2a_b, hhB, 512, 511);

  // set-0 score GEMM, dual epilogue -> scores A (layer0 prev) + B (layer1 prev)
  score_pass<<<1024, 512, 0, stream>>>(att, a2a_w, a2a_b, d2d_w, hhA, hhB, scA, scB);
  softmax512<<<256, 512, 0, stream>>>(scA);            // covers scA and scB
  att_res_pass<<<dim3(4, 128), 512, 0, stream>>>(att, scA, scB, arA, arB);
  cvt_bf<<<256, 256, 0, stream>>>(arA, nullptr, arAb);
  cvt_bf<<<256, 256, 0, stream>>>(arB, nullptr, arBb);

  // ---- layer 0 LSTM ----
  gates_gemm<<<dim3(16, 4), 256, 0, stream>>>(
      i2h_w, h2h_w, a2h_w, xt0b, ph0b, arAb, i2h_b, h2h_b, a2h_b, sums);
  lstm_combine<<<256, 256, 0, stream>>>(sums, prev_c0, out /*next_c0*/, nh0f, nh0b);

  // attend set-1 on next_h0
  gemm_tn512<<<dim3(2, 4), 256, 0, stream>>>(h2a1_w, nh0b, h2a1_b, hhC, 512, 511);
  score_pass<<<1024, 512, 0, stream>>>(att, a2a1_w, a2a1_b, d2d1_w, hhC, nullptr, scC, nullptr);
  softmax512<<<128, 512, 0, stream>>>(scC);
  att_res_pass<<<dim3(4, 128), 512, 0, stream>>>(att, scC, nullptr, arC, nullptr);
  add_store<<<256, 256, 0, stream>>>(arC, nh0f, out + S /*top_h0*/, nullptr);
  cvt_bf<<<256, 256, 0, stream>>>(x, out + S, xt1b);   // xt1 = x + top_h0

  // ---- layer 1 LSTM ----
  gates_gemm<<<dim3(16, 4), 256, 0, stream>>>(
      i2h_w + LSTRIDE_W, h2h_w + LSTRIDE_W, a2h_w + LSTRIDE_W,
      xt1b, ph1b, arBb,
      i2h_b + LSTRIDE_B, h2h_b + LSTRIDE_B, a2h_b + LSTRIDE_B, sums);
  lstm_combine<<<256, 256, 0, stream>>>(sums, prev_c1, out + 2 * S /*next_c1*/, nh1f, nh1b);

  // attend set-1 on next_h1
  gemm_tn512<<<dim3(2, 4), 256, 0, stream>>>(h2a1_w, nh1b, h2a1_b, hhD, 512, 511);
  score_pass<<<1024, 512, 0, stream>>>(att, a2a1_w, a2a1_b, d2d1_w, hhD, nullptr, scD, nullptr);
  softmax512<<<128, 512, 0, stream>>>(scD);
  att_res_pass<<<dim3(4, 128), 512, 0, stream>>>(att, scD, nullptr, arD, nullptr);
  add_store<<<256, 256, 0, stream>>>(arD, nh1f, out + 3 * S /*top_h1*/, th1b);

  // projection + log_softmax
  gemm_tn512<<<dim3(40, 4), 256, 0, stream>>>(proj_w, th1b, proj_b, logits, NOUT, NOUT - 1);
  logsoftmax_k<<<128, 256, 0, stream>>>(logits, out + 4 * S);
}